// Round 4
// baseline (23.286 us; speedup 1.0000x reference)
//
#include <hip/hip_runtime.h>

typedef float f32x2 __attribute__((ext_vector_type(2)));

namespace {
constexpr int R = 16;
constexpr int A = 4;
// ws layout: PKS[2][16] structs of 16 floats (64 B), pass-major:
//   [0..3]  m[a]                 (mean per antecedent)
//   [4..11] (kh,kl) per a        (k = -0.5*log2e/s^2, hi/lo interleaved)
//   [12]    c_sorted[k]
//   [13]    c_orig[k]            (unsorted c at position k)
//   [14,15] pad
}

__global__ __launch_bounds__(64) void t2fls_prep(
    const float* __restrict__ frb,
    const float* __restrict__ c1g,
    const float* __restrict__ c2g,
    float* __restrict__ ws)
{
    __shared__ float cbuf[2][R];
    __shared__ int   idxs[2][R];
    __shared__ float csort[2][R];
    const int t = threadIdx.x;
    if (t < 2 * R) { const int p = t >> 4, i = t & 15; cbuf[p][i] = p ? c2g[i] : c1g[i]; }
    __syncthreads();
    if (t < 2 * R) {
        const int p = t >> 4, i = t & 15;
        const float ci = cbuf[p][i];
        int rank = 0;
        for (int j = 0; j < R; ++j) {
            const float cj = cbuf[p][j];
            rank += (cj < ci) || (cj == ci && j < i);    // stable argsort
        }
        idxs[p][rank] = i; csort[p][rank] = ci;
    }
    __syncthreads();
    if (t < 2 * R) {
        const int p = t >> 4, k = t & 15;
        const int i = idxs[p][k];
        float* o = ws + (p * R + k) * 16;
        const float HL2E = 0.7213475204444817f;          // 0.5*log2(e)
        #pragma unroll
        for (int a = 0; a < A; ++a) {
            const float m  = frb[(i * A + a) * 3 + 0];
            const float s1 = frb[(i * A + a) * 3 + 1];
            const float s2 = frb[(i * A + a) * 3 + 2];
            const float slo = fminf(s1, s2), shi = fmaxf(s1, s2);
            o[a]         = m;
            o[4 + 2 * a]     = -HL2E / (shi * shi);      // kh
            o[4 + 2 * a + 1] = -HL2E / (slo * slo);      // kl
        }
        o[12] = csort[p][k];
        o[13] = cbuf[p][k];      // unsorted c at index k (reference pairs these)
        o[14] = 0.f; o[15] = 0.f;
    }
}

// One KM endpoint pass for ONE sample. Coefficients come from uniform P with
// compile-time offsets -> s_load (scalar pipe). (eU,eL),(s0,su),(ss,cn) are
// f32x2 pairs -> v_pk_fma_f32 where the backend packs them.
template<bool RIGHT>
__device__ __forceinline__ float km_pass(const float4 xv, const float* __restrict__ P)
{
    float d[R];
    f32x2 acc = {0.f, 0.f};      // (s0, su)
    float t0 = 0.f;
    #pragma unroll
    for (int k = 0; k < R; ++k) {
        const float* o = P + k * 16;
        f32x2 e = {0.f, 0.f};    // (eU, eL)
        {
            const float z = xv.x - o[0]; const float z2 = z * z;
            const f32x2 kk = {o[4], o[5]};  const f32x2 zz = {z2, z2};
            e += kk * zz;
        }
        {
            const float z = xv.y - o[1]; const float z2 = z * z;
            const f32x2 kk = {o[6], o[7]};  const f32x2 zz = {z2, z2};
            e += kk * zz;
        }
        {
            const float z = xv.z - o[2]; const float z2 = z * z;
            const f32x2 kk = {o[8], o[9]};  const f32x2 zz = {z2, z2};
            e += kk * zz;
        }
        {
            const float z = xv.w - o[3]; const float z2 = z * z;
            const f32x2 kk = {o[10], o[11]}; const f32x2 zz = {z2, z2};
            e += kk * zz;
        }
        const float uu = __builtin_amdgcn_exp2f(e.x);   // prod_a mu_hi
        const float ll = __builtin_amdgcn_exp2f(e.y);   // prod_a mu_lo
        const float w  = RIGHT ? uu : ll;
        const f32x2 cc = {o[12], o[13]};                // (c_sorted, c_orig)
        const f32x2 ww = {w, w};
        acc += cc * ww;                                 // s0 += cs*w; su += co*w
        t0 += w;
        d[k] = RIGHT ? (ll - uu) : (uu - ll);
    }
    // inclusive cumsum, k = 0
    f32x2 sc = {acc.x, 0.f};                            // (ss, cn)
    {
        const f32x2 cc = {P[12], P[13]};
        const f32x2 dd = {d[0], d[0]};
        sc += cc * dd;
    }
    float tt = t0 + d[0];
    f32x2 scb = sc; float tb = tt;
    const float tt0 = tt, cn0 = sc.y;
    #pragma unroll
    for (int k = 1; k < R; ++k) {
        const float* o = P + k * 16;
        const f32x2 cc = {o[12], o[13]};
        const f32x2 dd = {d[k], d[k]};
        sc += cc * dd;
        tt += d[k];
        // left:  ratio_k < best  <=>  ss*tb < sb*tt   (tt,tb > 0)
        // right: ratio_k > best  <=>  ss*tb > sb*tt
        const bool take = RIGHT ? ((sc.x * tb) > (scb.x * tt))
                                : ((sc.x * tb) < (scb.x * tt));
        if (take) { scb = sc; tb = tt; }                // first occurrence
    }
    // override to k=0 iff q0 dominates (left: q0 <= min; right: q0 >= max)
    const bool zero = RIGHT ? ((acc.x * tb) >= (scb.x * t0))
                            : ((acc.x * tb) <= (scb.x * t0));
    if (zero) { tb = tt0; scb.y = cn0; }
    // den = t0 + sum_{k<=loc} d = tb; rcp's ~1ulp fine at 2.8e-2 tolerance
    return (acc.y + scb.y) * __builtin_amdgcn_rcpf(tb);
}

// Two samples per thread (gid and gid+NHALF): two independent dependency
// chains fill the exp/fma latency; per-wave s_loads amortize over 2x work.
__global__ __launch_bounds__(256) void t2fls_main(
    const float* __restrict__ x,
    const float* __restrict__ P,
    float* __restrict__ out,
    int nhalf)
{
    const int gid = blockIdx.x * 256 + threadIdx.x;
    const float4 xA = reinterpret_cast<const float4*>(x)[gid];
    const float4 xB = reinterpret_cast<const float4*>(x)[gid + nhalf];

    const float lA = km_pass<false>(xA, P);
    const float lB = km_pass<false>(xB, P);
    const float rA = km_pass<true>(xA, P + R * 16);
    const float rB = km_pass<true>(xB, P + R * 16);

    out[gid]         = 0.5f * (lA + rA);
    out[gid + nhalf] = 0.5f * (lB + rB);
}

extern "C" void kernel_launch(void* const* d_in, const int* in_sizes, int n_in,
                              void* d_out, int out_size, void* d_ws, size_t ws_size,
                              hipStream_t stream) {
    const float* x   = (const float*)d_in[0];   // (N, 4) float32
    const float* frb = (const float*)d_in[1];   // (R*A*3,) float32
    const float* c1  = (const float*)d_in[2];   // (R,) float32
    const float* c2  = (const float*)d_in[3];   // (R,) float32
    float* out = (float*)d_out;                 // (N,) float32
    float* ws  = (float*)d_ws;                  // 2*16*16 floats = 2 KiB

    const int n = out_size;                     // N = 262144
    const int nhalf = n / 2;
    hipLaunchKernelGGL(t2fls_prep, dim3(1), dim3(64), 0, stream, frb, c1, c2, ws);
    const int blocks = nhalf / 256;             // 512
    hipLaunchKernelGGL(t2fls_main, dim3(blocks), dim3(256), 0, stream, x, ws, out, nhalf);
}

// Round 5
// 19.420 us; speedup vs baseline: 1.1991x; 1.1991x over previous
//
#include <hip/hip_runtime.h>

namespace {
constexpr int R = 16;
// d_ws float layout:
//  [0..255]   memb[p][16], p = pass-1 (idx1-sorted) position:
//             m[4], kh[4], kl[4], c1s[p], c1o[p], c2p[p], c2m[p]
//             kh/kl = -0.5*log2e/s^2 ; c1s=c1[idx1[p]] ; c1o=c1[p]
//             c2p=c2[idx1[p]] (proper pair) ; c2m=c2[rank2(idx1[p])] (ref mispair)
//  [256..271] pi_off[k] as int: rank1(idx2[k]) * 1024  (LDS row byte offset)
//  [272..287] negc2s[k] = -c2[idx2[k]]
//  [288..303] negc2o[k] = -c2[k]
constexpr int MEMB = 0;
constexpr int PIOF = 256;
constexpr int NC2S = 272;
constexpr int NC2O = 288;
}

__global__ __launch_bounds__(64) void t2fls_prep(
    const float* __restrict__ frb,
    const float* __restrict__ c1g,
    const float* __restrict__ c2g,
    float* __restrict__ ws)
{
    __shared__ float c1b[R], c2b[R];
    __shared__ int idx1[R], idx2[R], rk1[R], rk2[R];
    const int t = threadIdx.x;
    if (t < R) { c1b[t] = c1g[t]; c2b[t] = c2g[t]; }
    __syncthreads();
    if (t < 2 * R) {
        const int p = t >> 4, i = t & 15;
        const float* c = p ? c2b : c1b;
        const float ci = c[i];
        int rank = 0;
        for (int j = 0; j < R; ++j) {
            const float cj = c[j];
            rank += (cj < ci) || (cj == ci && j < i);   // stable argsort
        }
        if (!p) { idx1[rank] = i; rk1[i] = rank; }
        else    { idx2[rank] = i; rk2[i] = rank; }
    }
    __syncthreads();
    if (t < R) {
        const int p = t;              // pass-1 sorted position
        const int i = idx1[p];        // rule id
        float* o = ws + MEMB + p * 16;
        const float HL2E = 0.7213475204444817f;   // 0.5*log2(e)
        #pragma unroll
        for (int a = 0; a < 4; ++a) {
            const float m  = frb[(i * 4 + a) * 3 + 0];
            const float s1 = frb[(i * 4 + a) * 3 + 1];
            const float s2 = frb[(i * 4 + a) * 3 + 2];
            const float slo = fminf(s1, s2), shi = fmaxf(s1, s2);
            o[a]     = m;
            o[4 + a] = -HL2E * __builtin_amdgcn_rcpf(shi * shi);
            o[8 + a] = -HL2E * __builtin_amdgcn_rcpf(slo * slo);
        }
        o[12] = c1b[i];               // c1s[p]
        o[13] = c1b[p];               // c1o[p]  (reference's unsorted-c pairing)
        o[14] = c2b[i];               // c2p[p]  (proper pair, for s0R)
        o[15] = c2b[rk2[i]];          // c2m[p]  (mispair, for suR)
        // pass-2 scan tables (k = t)
        reinterpret_cast<int*>(ws)[PIOF + t] = rk1[idx2[t]] * 1024;
        ws[NC2S + t] = -c2b[idx2[t]];
        ws[NC2O + t] = -c2b[t];
    }
}

// One thread per sample. Memberships computed ONCE per rule (idx1 order);
// both endpoints' base sums accumulated in the same loop. Left scan on
// register d1[]; right scan reads the idx2-permuted d via per-thread LDS
// column (no barriers, no cross-thread sharing).
__global__ __launch_bounds__(256) void t2fls_main(
    const float* __restrict__ x,
    const float* __restrict__ P,
    float* __restrict__ out)
{
    __shared__ float dls[R][256];     // [rule-pos][thread] : conflict-free (2 lanes/bank)
    const int t = threadIdx.x;
    const int gid = blockIdx.x * 256 + t;
    const float4 xv = reinterpret_cast<const float4*>(x)[gid];

    float d1[R];
    float s0L = 0.f, t0L = 0.f, suL = 0.f;
    float s0R = 0.f, t0R = 0.f, suR = 0.f;
    #pragma unroll
    for (int p = 0; p < R; ++p) {
        const float* o = P + MEMB + p * 16;       // compile-time offsets -> s_load
        const float z0 = xv.x - o[0], z1 = xv.y - o[1];
        const float z2 = xv.z - o[2], z3 = xv.w - o[3];
        const float q0 = z0 * z0, q1 = z1 * z1, q2 = z2 * z2, q3 = z3 * z3;
        float eU = o[4] * q0;
        eU = fmaf(o[5], q1, eU); eU = fmaf(o[6], q2, eU); eU = fmaf(o[7], q3, eU);
        float eL = o[8] * q0;
        eL = fmaf(o[9], q1, eL); eL = fmaf(o[10], q2, eL); eL = fmaf(o[11], q3, eL);
        const float uu = __builtin_amdgcn_exp2f(eU);   // prod_a mu_hi
        const float ll = __builtin_amdgcn_exp2f(eL);   // prod_a mu_lo
        s0L = fmaf(o[12], ll, s0L);
        t0L += ll;
        suL = fmaf(o[13], ll, suL);
        s0R = fmaf(o[14], uu, s0R);
        t0R += uu;
        suR = fmaf(o[15], uu, suR);
        const float dv = uu - ll;                      // dv >= 0
        d1[p] = dv;
        dls[p][t] = dv;                                // imm-offset ds_write_b32
    }

    // ---------------- left endpoint: scan in idx1 order (registers) --------
    float left;
    {
        float ss = fmaf(P[MEMB + 12], d1[0], s0L);
        float tt = t0L + d1[0];
        float cn = P[MEMB + 13] * d1[0];
        float sb = ss, tb = tt, cnb = cn;
        const float tt0 = tt, cn0 = cn;
        #pragma unroll
        for (int k = 1; k < R; ++k) {
            ss = fmaf(P[MEMB + k * 16 + 12], d1[k], ss);
            tt += d1[k];
            cn = fmaf(P[MEMB + k * 16 + 13], d1[k], cn);
            // ratio_k < best  <=>  ss*tb < sb*tt  (tt,tb > 0)
            if ((ss * tb) < (sb * tt)) { sb = ss; tb = tt; cnb = cn; }
        }
        if ((s0L * tb) <= (sb * t0L)) { tb = tt0; cnb = cn0; }   // q0 dominates -> loc 0
        left = (suL + cnb) * __builtin_amdgcn_rcpf(tb);
    }

    // ---------------- right endpoint: permuted d via LDS column ------------
    const int* Pi = reinterpret_cast<const int*>(P);
    float dv[R];
    const char* colbase = reinterpret_cast<const char*>(&dls[0][t]);
    #pragma unroll
    for (int k = 0; k < R; ++k) {
        // runtime-uniform row offset (s_load) + per-thread column base
        dv[k] = *reinterpret_cast<const float*>(colbase + Pi[PIOF + k]);
    }
    float right;
    {
        // dr[k] = -dv[k]; signs folded into negated coefficients / subtract
        float ss = fmaf(P[NC2S + 0], dv[0], s0R);
        float tt = t0R - dv[0];
        float cn = P[NC2O + 0] * dv[0];
        float sb = ss, tb = tt, cnb = cn;
        const float tt0 = tt, cn0 = cn;
        #pragma unroll
        for (int k = 1; k < R; ++k) {
            ss = fmaf(P[NC2S + k], dv[k], ss);
            tt -= dv[k];
            cn = fmaf(P[NC2O + k], dv[k], cn);
            // ratio_k > best  <=>  ss*tb > sb*tt  (tt,tb > 0)
            if ((ss * tb) > (sb * tt)) { sb = ss; tb = tt; cnb = cn; }
        }
        if ((s0R * tb) >= (sb * t0R)) { tb = tt0; cnb = cn0; }   // q0 dominates -> loc 0
        right = (suR + cnb) * __builtin_amdgcn_rcpf(tb);
    }

    out[gid] = 0.5f * (left + right);
}

extern "C" void kernel_launch(void* const* d_in, const int* in_sizes, int n_in,
                              void* d_out, int out_size, void* d_ws, size_t ws_size,
                              hipStream_t stream) {
    const float* x   = (const float*)d_in[0];   // (N, 4) float32
    const float* frb = (const float*)d_in[1];   // (R*A*3,) float32
    const float* c1  = (const float*)d_in[2];   // (R,) float32
    const float* c2  = (const float*)d_in[3];   // (R,) float32
    float* out = (float*)d_out;                 // (N,) float32
    float* ws  = (float*)d_ws;                  // 304 floats = 1216 B

    const int n = out_size;                     // N = 262144 (multiple of 256)
    hipLaunchKernelGGL(t2fls_prep, dim3(1), dim3(64), 0, stream, frb, c1, c2, ws);
    hipLaunchKernelGGL(t2fls_main, dim3(n / 256), dim3(256), 0, stream, x, ws, out);
}

// Round 6
// 14.355 us; speedup vs baseline: 1.6222x; 1.3528x over previous
//
#include <hip/hip_runtime.h>

namespace {
constexpr int R = 16;

__device__ __forceinline__ float rdlanef(float v, int lane) {
    return __int_as_float(__builtin_amdgcn_readlane(__float_as_int(v), lane));
}
__device__ __forceinline__ int rdlanei(float v, int lane) {
    return __builtin_amdgcn_readlane(__float_as_int(v), lane);
}
__device__ __forceinline__ float bpermf(float v, int srclane) {
    return __int_as_float(__builtin_amdgcn_ds_bpermute(srclane * 4, __float_as_int(v)));
}
__device__ __forceinline__ int bpermi(int v, int srclane) {
    return __builtin_amdgcn_ds_bpermute(srclane * 4, v);
}
}

// Single fused kernel. Each WAVE redundantly computes prep (~200 instrs, no
// barriers, wave-synchronous): stable ranks via bpermute, permutation invert
// via one ds_permute push, per-lane frb loads + transforms. Rule p's params
// live in lane p's VGPRs (pr0..pr15); pass-2 scan tables in lanes 16..31.
// Hot loop streams them with v_readlane (constant lane -> SGPR; each fma uses
// exactly 1 SGPR operand). NO second dispatch, NO param LDS traffic.
__global__ __launch_bounds__(256) void t2fls_fused(
    const float* __restrict__ x,
    const float* __restrict__ frb,
    const float* __restrict__ c1g,
    const float* __restrict__ c2g,
    float* __restrict__ out)
{
    __shared__ float dls[R][256];          // d-permutation column file (16 KB)
    const int tid  = threadIdx.x;
    const int gid  = blockIdx.x * 256 + tid;
    const float4 xv = reinterpret_cast<const float4*>(x)[gid];   // issue early

    const int lane = tid & 63;
    const int sub  = lane & 15;            // position within 16-group
    const int p2   = (lane >> 4) & 1;      // 0: c1 pass, 1: c2 pass
    const int quad = lane & 48;            // duplicate quadrants (32-63 mirror 0-31)

    // ---- per-wave prep ----------------------------------------------------
    const float ci = (p2 ? c2g : c1g)[sub];          // own c value
    int rank = 0;
    #pragma unroll
    for (int j = 0; j < R; ++j) {
        const float cj = bpermf(ci, p2 * 16 + j);    // c_pass[j]
        rank += (cj < ci || (cj == ci && j < sub)) ? 1 : 0;   // stable argsort
    }
    // invert: lane (quad|rank) receives i = idx_pass[rank]
    const int i = __builtin_amdgcn_ds_permute((quad + rank) * 4, sub);

    // cross-lane coefficient pulls (src lanes 0..31 hold real data)
    const float c1s = bpermf(ci, i);                 // c1[idx1[p]]   (group0 use)
    const float c2p = bpermf(ci, 16 + i);            // c2[i]: group0 c2[idx1[p]], group1 c2s[k]
    const int   r2i = bpermi(rank, 16 + i);          // rk2[i]        (group0 use)
    const float c2m = bpermf(ci, 16 + r2i);          // c2[rk2[idx1[p]]] (ref mispair)
    const int   r1i = bpermi(rank, i);               // rk1[i]: group1 -> rk1[idx2[k]]
    const int pioff = r1i << 10;                     // dls row byte offset (256*4)

    // per-lane rule load + Gaussian transforms (group1 lanes waste this, fine)
    const float* fb = frb + i * 12;                  // 48B-aligned -> float4 ok
    const float4 f0 = *reinterpret_cast<const float4*>(fb);
    const float4 f1 = *reinterpret_cast<const float4*>(fb + 4);
    const float4 f2 = *reinterpret_cast<const float4*>(fb + 8);
    // layout: rule i, antecedent a: [i*12 + a*3 + {m,s1,s2}]
    const float HL2E = 0.7213475204444817f;          // 0.5*log2(e)
    float mm[4], kh[4], kl[4];
    {
        const float m_[4]  = {f0.x, f0.w, f1.z, f2.y};
        const float s1_[4] = {f0.y, f1.x, f1.w, f2.z};
        const float s2_[4] = {f0.z, f1.y, f2.x, f2.w};
        #pragma unroll
        for (int a = 0; a < 4; ++a) {
            const float slo = fminf(s1_[a], s2_[a]);
            const float shi = fmaxf(s1_[a], s2_[a]);
            mm[a] = m_[a];
            kh[a] = -HL2E * __builtin_amdgcn_rcpf(shi * shi);
            kl[a] = -HL2E * __builtin_amdgcn_rcpf(slo * slo);
        }
    }
    // param register file: lane p -> rule p (group0); lane 16+k -> scan tables
    const bool g1 = (lane & 16) != 0;
    const float pr0  = g1 ? __int_as_float(pioff) : mm[0];
    const float pr1  = mm[1], pr2 = mm[2], pr3 = mm[3];
    const float pr4  = kh[0], pr5 = kh[1], pr6 = kh[2], pr7 = kh[3];
    const float pr8  = kl[0], pr9 = kl[1], pr10 = kl[2], pr11 = kl[3];
    const float pr12 = c1s;   // c1 sorted
    const float pr13 = ci;    // own c: group0 c1[p] (mispair), group1 c2[k]
    const float pr14 = c2p;   // group0 c2[idx1[p]], group1 c2[idx2[k]]
    const float pr15 = c2m;   // group0 mispaired c2

    // ---- membership + base sums (idx1 order), d into regs + LDS column ----
    float d1[R];
    float s0L = 0.f, t0L = 0.f, suL = 0.f;
    float s0R = 0.f, t0R = 0.f, suR = 0.f;
    #pragma unroll
    for (int p = 0; p < R; ++p) {
        const float z0 = xv.x - rdlanef(pr0, p);
        const float z1 = xv.y - rdlanef(pr1, p);
        const float z2 = xv.z - rdlanef(pr2, p);
        const float z3 = xv.w - rdlanef(pr3, p);
        const float q0 = z0 * z0, q1 = z1 * z1, q2 = z2 * z2, q3 = z3 * z3;
        float eU = rdlanef(pr4, p) * q0;
        eU = fmaf(rdlanef(pr5, p), q1, eU);
        eU = fmaf(rdlanef(pr6, p), q2, eU);
        eU = fmaf(rdlanef(pr7, p), q3, eU);
        float eL = rdlanef(pr8, p) * q0;
        eL = fmaf(rdlanef(pr9, p), q1, eL);
        eL = fmaf(rdlanef(pr10, p), q2, eL);
        eL = fmaf(rdlanef(pr11, p), q3, eL);
        const float uu = __builtin_amdgcn_exp2f(eU);   // prod_a mu_hi
        const float ll = __builtin_amdgcn_exp2f(eL);   // prod_a mu_lo
        s0L = fmaf(rdlanef(pr12, p), ll, s0L);
        t0L += ll;
        suL = fmaf(rdlanef(pr13, p), ll, suL);
        s0R = fmaf(rdlanef(pr14, p), uu, s0R);
        t0R += uu;
        suR = fmaf(rdlanef(pr15, p), uu, suR);
        const float dv = uu - ll;                      // dv >= 0
        d1[p] = dv;
        dls[p][tid] = dv;                              // imm-offset ds_write_b32
    }

    // ---- left endpoint: scan in idx1 order (registers) --------------------
    float left;
    {
        float ss = fmaf(rdlanef(pr12, 0), d1[0], s0L);
        float tt = t0L + d1[0];
        float cn = rdlanef(pr13, 0) * d1[0];
        float sb = ss, tb = tt, cnb = cn;
        const float tt0 = tt, cn0 = cn;
        #pragma unroll
        for (int k = 1; k < R; ++k) {
            ss = fmaf(rdlanef(pr12, k), d1[k], ss);
            tt += d1[k];
            cn = fmaf(rdlanef(pr13, k), d1[k], cn);
            if ((ss * tb) < (sb * tt)) { sb = ss; tb = tt; cnb = cn; }  // first-occ argmin
        }
        if ((s0L * tb) <= (sb * t0L)) { tb = tt0; cnb = cn0; }  // q0 dominates -> loc 0
        left = (suL + cnb) * __builtin_amdgcn_rcpf(tb);
    }

    // ---- right endpoint: idx2-permuted d via per-thread LDS column --------
    float dv[R];
    const char* colbase = reinterpret_cast<const char*>(&dls[0][tid]);
    #pragma unroll
    for (int k = 0; k < R; ++k) {
        const int off = rdlanei(pr0, 16 + k);          // rk1[idx2[k]]*1024 (SGPR)
        dv[k] = *reinterpret_cast<const float*>(colbase + off);
    }
    float right;
    {
        // dr[k] = -dv[k]; signs folded via negated SGPR operands
        float ss = fmaf(-rdlanef(pr14, 16), dv[0], s0R);
        float tt = t0R - dv[0];
        float cn = -rdlanef(pr13, 16) * dv[0];
        float sb = ss, tb = tt, cnb = cn;
        const float tt0 = tt, cn0 = cn;
        #pragma unroll
        for (int k = 1; k < R; ++k) {
            ss = fmaf(-rdlanef(pr14, 16 + k), dv[k], ss);
            tt -= dv[k];
            cn = fmaf(-rdlanef(pr13, 16 + k), dv[k], cn);
            if ((ss * tb) > (sb * tt)) { sb = ss; tb = tt; cnb = cn; }  // first-occ argmax
        }
        if ((s0R * tb) >= (sb * t0R)) { tb = tt0; cnb = cn0; }  // q0 dominates -> loc 0
        right = (suR + cnb) * __builtin_amdgcn_rcpf(tb);
    }

    out[gid] = 0.5f * (left + right);
}

extern "C" void kernel_launch(void* const* d_in, const int* in_sizes, int n_in,
                              void* d_out, int out_size, void* d_ws, size_t ws_size,
                              hipStream_t stream) {
    const float* x   = (const float*)d_in[0];   // (N, 4) float32
    const float* frb = (const float*)d_in[1];   // (R*A*3,) float32
    const float* c1  = (const float*)d_in[2];   // (R,) float32
    const float* c2  = (const float*)d_in[3];   // (R,) float32
    float* out = (float*)d_out;                 // (N,) float32

    const int n = out_size;                     // N = 262144 (multiple of 256)
    hipLaunchKernelGGL(t2fls_fused, dim3(n / 256), dim3(256), 0, stream,
                       x, frb, c1, c2, out);
}